// Round 8
// baseline (723.569 us; speedup 1.0000x reference)
//
#include <hip/hip_runtime.h>
#include <stdint.h>

typedef __bf16 bf16;
typedef __bf16   bf16x4 __attribute__((ext_vector_type(4)));
typedef __bf16   bf16x8 __attribute__((ext_vector_type(8)));
typedef short    s16x8  __attribute__((ext_vector_type(8)));
typedef float    fx4    __attribute__((ext_vector_type(4)));

#define NB 32
#define NT 1500
#define NF 512
#define NM (NB*NT)      // 48000
#define KW 31
#define EPSF 1e-5f

__device__ __forceinline__ float dscale(const float* a) {
  return fmaxf(a[0] * (1.0f/127.0f), 1e-8f);
}
__device__ __forceinline__ float fq_int(float x, float inv_s) {
  return fminf(fmaxf(rintf(x*inv_s), -128.0f), 127.0f);
}
__device__ __forceinline__ void block_amax(float v, float* dst) {
  __shared__ float red[8];
  #pragma unroll
  for (int o = 32; o > 0; o >>= 1) v = fmaxf(v, __shfl_xor(v, o));
  if ((threadIdx.x & 63) == 0) red[threadIdx.x >> 6] = v;
  __syncthreads();
  if (threadIdx.x == 0) {
    int nw = blockDim.x >> 6;
    float m = red[0];
    for (int i = 1; i < nw; i++) m = fmaxf(m, red[i]);
    atomicMax((unsigned int*)dst, __float_as_uint(m));
  }
}

__device__ __forceinline__ float amax_loop(const float* p, long n4, int bid, int gsz) {
  float am = 0.f;
  long i = (long)bid * blockDim.x + threadIdx.x;
  long stride = (long)gsz * blockDim.x;
  for (; i < n4; i += stride) {
    fx4 v = ((const fx4*)p)[i];
    #pragma unroll
    for (int j = 0; j < 4; j++) am = fmaxf(am, fabsf(v[j]));
  }
  return am;
}
// ---------- merged weight absmax (W1, W2, dw) ----------
__global__ void absmax_w(const float* __restrict__ W1, const float* __restrict__ W2,
                         const float* __restrict__ dwp, float* a) {
  int bx = blockIdx.x;
  float am; float* dst;
  if (bx < 256)      { am = amax_loop(W1,  131072, bx,       256); dst = a + 1; }
  else if (bx < 384) { am = amax_loop(W2,  65536,  bx - 256, 128); dst = a + 2; }
  else               { am = amax_loop(dwp, 3968,   bx - 384, 8);   dst = a + 3; }
  block_amax(am, dst);
}

// ---------- quantize fp32 [R x 512] -> integer-grid bf16 in MFMA-fragment-packed layout ----
// Panel (r16, kb) = 16 rows x 32 k, stored as 1KB contiguous chunk of 64 x 8 bf16.
__global__ void quant_pack(const float* __restrict__ src, bf16* __restrict__ dst,
                           int R, const float* amax) {
  float inv_s = 1.0f / dscale(amax);
  int total = R * 64;                       // one thread per 8-element chunk
  for (int t = blockIdx.x*blockDim.x + threadIdx.x; t < total; t += gridDim.x*blockDim.x) {
    int r = t >> 6, q8 = t & 63;            // read coalesced: row r, cols q8*8..+7
    const float* s = src + (size_t)r*512 + q8*8;
    fx4 v0 = *(const fx4*)s, v1 = *(const fx4*)(s+4);
    bf16x8 o;
    #pragma unroll
    for (int j = 0; j < 4; j++) { o[j] = (bf16)fq_int(v0[j], inv_s); o[4+j] = (bf16)fq_int(v1[j], inv_s); }
    int r16 = r >> 4, m16 = r & 15, kb = q8 >> 2, quad = q8 & 3;
    size_t chunk = ((size_t)r16*16 + kb)*64 + quad*16 + m16;
    ((bf16x8*)dst)[chunk] = o;
  }
}

// ---------- final fake-quant fp32 in place ----------
__global__ void quant_deq_f32(float* __restrict__ p, long n4, const float* amax) {
  float s = dscale(amax);
  float inv_s = 1.0f / s;
  long i = (long)blockIdx.x * blockDim.x + threadIdx.x;
  long stride = (long)gridDim.x * blockDim.x;
  for (; i < n4; i += stride) {
    fx4 v = ((fx4*)p)[i];
    fx4 o;
    #pragma unroll
    for (int j = 0; j < 4; j++) o[j] = fq_int(v[j], inv_s) * s;
    ((fx4*)p)[i] = o;
  }
}

// ---------- LayerNorm pass 1: amax only (no stores) ----------
__global__ void ln_amax_k(const float* __restrict__ x, const float* __restrict__ g,
                          const float* __restrict__ be, float* amax) {
  int lane = threadIdx.x & 63;
  int wavesTotal = (gridDim.x * blockDim.x) >> 6;
  int wave = ((blockIdx.x * blockDim.x) + threadIdx.x) >> 6;
  fx4 g0 = ((const fx4*)g)[2*lane],  g1 = ((const fx4*)g)[2*lane+1];
  fx4 b0 = ((const fx4*)be)[2*lane], b1v = ((const fx4*)be)[2*lane+1];
  float gf[8], bff[8];
  #pragma unroll
  for (int j = 0; j < 4; j++) { gf[j] = g0[j]; gf[4+j] = g1[j]; bff[j] = b0[j]; bff[4+j] = b1v[j]; }
  float am = 0.f;
  for (int row = wave; row < NM; row += wavesTotal) {
    const fx4* xr = (const fx4*)(x + (long)row*NF);
    fx4 x0 = xr[2*lane], x1 = xr[2*lane+1];
    float xf[8]; float s = 0.f;
    #pragma unroll
    for (int j = 0; j < 4; j++) { xf[j] = x0[j]; xf[4+j] = x1[j]; }
    #pragma unroll
    for (int j = 0; j < 8; j++) s += xf[j];
    #pragma unroll
    for (int o = 32; o > 0; o >>= 1) s += __shfl_xor(s, o);
    float mu = s * (1.0f/NF);
    float vs = 0.f;
    #pragma unroll
    for (int j = 0; j < 8; j++) { float d = xf[j]-mu; vs += d*d; }
    #pragma unroll
    for (int o = 32; o > 0; o >>= 1) vs += __shfl_xor(vs, o);
    float inv = rsqrtf(vs*(1.0f/NF) + EPSF);
    #pragma unroll
    for (int j = 0; j < 8; j++) {
      float v = (xf[j]-mu)*inv*gf[j] + bff[j];
      am = fmaxf(am, fabsf(v));
    }
  }
  block_amax(am, amax);
}

// ---------- LayerNorm pass 2: recompute + quantize + packed store (no t_raw) ----
__global__ void ln_pack_k(const float* __restrict__ x, const float* __restrict__ g,
                          const float* __restrict__ be, bf16* __restrict__ dst,
                          const float* amax) {
  int lane = threadIdx.x & 63;
  int wavesTotal = (gridDim.x * blockDim.x) >> 6;
  int wave = ((blockIdx.x * blockDim.x) + threadIdx.x) >> 6;
  float inv_s = 1.0f / dscale(amax);
  fx4 g0 = ((const fx4*)g)[2*lane],  g1 = ((const fx4*)g)[2*lane+1];
  fx4 b0 = ((const fx4*)be)[2*lane], b1v = ((const fx4*)be)[2*lane+1];
  float gf[8], bff[8];
  #pragma unroll
  for (int j = 0; j < 4; j++) { gf[j] = g0[j]; gf[4+j] = g1[j]; bff[j] = b0[j]; bff[4+j] = b1v[j]; }
  for (int row = wave; row < NM; row += wavesTotal) {
    const fx4* xr = (const fx4*)(x + (long)row*NF);
    fx4 x0 = xr[2*lane], x1 = xr[2*lane+1];
    float xf[8]; float s = 0.f;
    #pragma unroll
    for (int j = 0; j < 4; j++) { xf[j] = x0[j]; xf[4+j] = x1[j]; }
    #pragma unroll
    for (int j = 0; j < 8; j++) s += xf[j];
    #pragma unroll
    for (int o = 32; o > 0; o >>= 1) s += __shfl_xor(s, o);
    float mu = s * (1.0f/NF);
    float vs = 0.f;
    #pragma unroll
    for (int j = 0; j < 8; j++) { float d = xf[j]-mu; vs += d*d; }
    #pragma unroll
    for (int o = 32; o > 0; o >>= 1) vs += __shfl_xor(vs, o);
    float inv = rsqrtf(vs*(1.0f/NF) + EPSF);
    bf16x8 o8;
    #pragma unroll
    for (int j = 0; j < 8; j++) {
      float v = (xf[j]-mu)*inv*gf[j] + bff[j];
      o8[j] = (bf16)fq_int(v, inv_s);
    }
    int r16 = row >> 4, m16 = row & 15;
    size_t chunk = ((size_t)r16*16 + (lane>>2))*64 + (lane&3)*16 + m16;
    ((bf16x8*)dst)[chunk] = o8;
  }
}

// ---------- MFMA GEMM: 3-deep global_load_lds pipeline with COUNTED vmcnt ----------
// BK=32 stages: 16 panels x 1KB (8 A + 8 B) per stage, 3 stage buffers (48KB).
// Raw s_barrier + asm vmcnt(8) keeps 2 stages in flight across barriers (the
// round-3 failure was __syncthreads draining vmcnt(0) each step).
// MODE 0: output C^T[N][M].  MODE 1: swapped mfma -> row-major C[M][N].
template<int NBN, int MODE>   // N = NBN*128
__global__ __launch_bounds__(256) void gemm_k(
    const bf16* __restrict__ A, const bf16* __restrict__ Bt,
    const float* __restrict__ bias, float* __restrict__ C,
    const float* amaxA, const float* amaxB, float* amaxC) {
  const int N = NBN * 128;
  int id = blockIdx.x;
  int bn = (id >> 3) % NBN;
  int bm = 8 * (id / (8 * NBN)) + (id & 7);
  if (bm >= 375) return;
  int lane = threadIdx.x & 63;
  int w = threadIdx.x >> 6;
  int wm = w >> 1, wn = w & 1;
  int quad = lane >> 4;
  int m16 = lane & 15;

  __shared__ __align__(16) char smem[49152];   // 3 x 16KB stages; epilogue aliases

  fx4 acc[4][4];
  #pragma unroll
  for (int i = 0; i < 4; i++)
    #pragma unroll
    for (int j = 0; j < 4; j++) acc[i][j] = fx4{0.f,0.f,0.f,0.f};

  const bf16* gA = A  + (size_t)(bm*8)*16*512;   // + p*8192 + kb*512 + lane*8
  const bf16* gB = Bt + (size_t)(bn*8)*16*512;

  auto issue = [&](int kb) {
    int b = kb % 3;
    #pragma unroll
    for (int q = 0; q < 4; q++) {
      int p = w*4 + q;                     // wave w stages panels 4w..4w+3
      const bf16* src = (p < 8)
          ? (gA + (size_t)p*8192     + (size_t)kb*512 + lane*8)
          : (gB + (size_t)(p-8)*8192 + (size_t)kb*512 + lane*8);
      __builtin_amdgcn_global_load_lds(
          (const __attribute__((address_space(1))) void*)src,
          (__attribute__((address_space(3))) void*)(smem + b*16384 + p*1024 + lane*16),
          16, 0, 0);
    }
  };

  issue(0); issue(1); issue(2);            // 12 loads/wave in flight

  #pragma unroll
  for (int kb = 0; kb < 16; kb++) {
    // wait for OWN stage-kb loads (keep newer stages in flight), then barrier
    if (kb <= 13)      asm volatile("s_waitcnt vmcnt(8)" ::: "memory");
    else if (kb == 14) asm volatile("s_waitcnt vmcnt(4)" ::: "memory");
    else               asm volatile("s_waitcnt vmcnt(0)" ::: "memory");
    __builtin_amdgcn_sched_barrier(0);
    __builtin_amdgcn_s_barrier();          // all waves' stage-kb loads landed
    __builtin_amdgcn_sched_barrier(0);
    char* buf = smem + (kb % 3)*16384;
    s16x8 aF[4], bF[4];
    #pragma unroll
    for (int i = 0; i < 4; i++) aF[i] = *(const s16x8*)(buf + (wm*4 + i)*1024 + lane*16);
    #pragma unroll
    for (int j = 0; j < 4; j++) bF[j] = *(const s16x8*)(buf + (8 + wn*4 + j)*1024 + lane*16);
    #pragma unroll
    for (int i = 0; i < 4; i++)
      #pragma unroll
      for (int j = 0; j < 4; j++) {
        if (MODE == 0)
          acc[i][j] = __builtin_amdgcn_mfma_f32_16x16x32_bf16(aF[i], bF[j], acc[i][j], 0, 0, 0);
        else
          acc[i][j] = __builtin_amdgcn_mfma_f32_16x16x32_bf16(bF[j], aF[i], acc[i][j], 0, 0, 0);
      }
    asm volatile("s_waitcnt lgkmcnt(0)" ::: "memory");   // reads done before overwrite
    __builtin_amdgcn_sched_barrier(0);
    __builtin_amdgcn_s_barrier();          // all waves done reading buf
    __builtin_amdgcn_sched_barrier(0);
    if (kb + 3 < 16) issue(kb + 3);        // refill same buffer slot
  }
  __syncthreads();                          // full drain before epilogue aliasing

  float (*ebuf)[32][132] = (float (*)[32][132])smem;   // [2][32][132] = 33792B

  float ab = dscale(amaxA) * dscale(amaxB);
  float am = 0.f;
  // which half-buffer this wave fills; which 16-row slice it drains
  const int h     = (MODE == 0) ? wn : wm;
  const int other = (MODE == 0) ? wm : wn;

  #pragma unroll
  for (int rnd = 0; rnd < 2; rnd++) {
    __syncthreads();                 // prev round's reads done before overwrite
    if (MODE == 0) {
      // out-row = N col; within = M. acc[i][j]: col=wn*64+j*16+m16, m=wm*64+i*16+quad*4
      #pragma unroll
      for (int jj = 0; jj < 2; jj++) {
        int j = rnd*2 + jj;
        int col = bn*128 + wn*64 + j*16 + m16;
        float bv = bias[col];
        #pragma unroll
        for (int i = 0; i < 4; i++) {
          fx4 o;
          #pragma unroll
          for (int rr = 0; rr < 4; rr++) {
            float v = acc[i][j][rr]*ab + bv;
            am = fmaxf(am, fabsf(v)); o[rr] = v;
          }
          *(fx4*)&ebuf[h][jj*16 + m16][wm*64 + i*16 + quad*4] = o;
        }
      }
    } else {
      // out-row = M; within = N. acc[i][j]: m=wm*64+i*16+m16, n=wn*64+j*16+quad*4
      #pragma unroll
      for (int ii = 0; ii < 2; ii++) {
        int i = rnd*2 + ii;
        #pragma unroll
        for (int j = 0; j < 4; j++) {
          int n0 = bn*128 + wn*64 + j*16 + quad*4;
          fx4 bv = *(const fx4*)(bias + n0);
          fx4 o;
          #pragma unroll
          for (int rr = 0; rr < 4; rr++) {
            float v = acc[i][j][rr]*ab + bv[rr];
            am = fmaxf(am, fabsf(v)); o[rr] = v;
          }
          *(fx4*)&ebuf[h][ii*16 + m16][wn*64 + j*16 + quad*4] = o;
        }
      }
    }
    __syncthreads();
    // drain: wave reads its 16-row slice of buffer h, 2 rows x 512B per store
    #pragma unroll
    for (int it = 0; it < 8; it++) {
      int lrow = other*16 + it*2 + (lane >> 5);
      int cf = (lane & 31) * 4;
      fx4 o = *(const fx4*)&ebuf[h][lrow][cf];
      int orow = ((MODE == 0) ? bn*128 : bm*128) + h*64 + rnd*32 + lrow;
      size_t base = (MODE == 0) ? ((size_t)orow*NM + (size_t)bm*128 + cf)
                                : ((size_t)orow*N  + (size_t)bn*128 + cf);
      *(fx4*)(C + base) = o;
    }
  }
  block_amax(am, amaxC);
}

// ---------- GLU from uT [1024][48000] -> v[B,F,T], pure streaming ----------
__global__ void glu_k(const float* __restrict__ uT, float* __restrict__ v,
                      const float* amaxU, float* amaxV) {
  float s = dscale(amaxU);
  float inv_s = 1.0f / s;
  float am = 0.f;
  const int tid = threadIdx.x;
  const int npairs = (NB*NF)/2;     // 8192 pairs of (b,f) rows
  for (int pr = blockIdx.x; pr < npairs; pr += gridDim.x) {
    int row0 = pr*2;
    for (int i = tid; i < 750; i += 256) {
      int r2 = (i >= 375) ? 1 : 0;
      int c = i - 375*r2;
      int row = row0 + r2;                 // row = b*NF + f
      int b = row >> 9, f = row & (NF-1);
      long bt = (long)b*NT + c*4;
      fx4 a = *(const fx4*)(uT + (long)f*NM + bt);
      fx4 g = *(const fx4*)(uT + (long)(f+NF)*NM + bt);
      fx4 o;
      #pragma unroll
      for (int j = 0; j < 4; j++) {
        float av = fq_int(a[j], inv_s) * s;
        float gv = fq_int(g[j], inv_s) * s;
        float val = av * (1.0f/(1.0f + expf(-gv)));
        am = fmaxf(am, fabsf(val));
        o[j] = val;
      }
      *(fx4*)(v + (long)row*NT + c*4) = o;
    }
  }
  block_amax(am, amaxV);
}

// ---------- depthwise conv K=31 on [B,F,T] ----------
__global__ void dwconv_k(const float* __restrict__ v, const float* __restrict__ w,
                         const float* __restrict__ wb, float* __restrict__ y,
                         const float* amaxV, const float* amaxW, float* amaxY) {
  __shared__ float z[2][1568];     // [row][16 left pad + 1500 + right pad]
  __shared__ float wl[2][32];
  float sv = dscale(amaxV); float inv_sv = 1.0f/sv;
  float sw = dscale(amaxW); float inv_sw = 1.0f/sw;
  float am = 0.f;
  const int tid = threadIdx.x;
  const int rr = tid >> 7;          // which row of the pair this thread computes
  const int cl = tid & 127;         // chunk lane within the half
  const int npairs = (NB*NF)/2;     // 8192
  for (int pr = blockIdx.x; pr < npairs; pr += gridDim.x) {
    int row0 = pr*2;
    __syncthreads();
    if (tid < 64) {
      int r2 = tid >> 5, k = tid & 31;
      if (k < KW) {
        int f = (row0 + r2) & (NF-1);
        wl[r2][k] = fq_int(w[f*KW + k], inv_sw) * sw;
      }
    }
    if (tid < 128) {
      int r2 = tid >> 6, jj = tid & 63;
      if (jj < 16) z[r2][jj] = 0.f;
      else         z[r2][1500 + jj] = 0.f;
    }
    const fx4* vp = (const fx4*)(v + (long)row0 * NT);
    for (int i = tid; i < 750; i += 256) {
      fx4 q = vp[i];
      int r2 = (i >= 375) ? 1 : 0;
      int ii = i - 375*r2;
      fx4 o;
      #pragma unroll
      for (int j = 0; j < 4; j++) o[j] = fq_int(q[j], inv_sv) * sv;
      *(fx4*)&z[r2][16 + 4*ii] = o;
    }
    __syncthreads();
    float wr[KW];
    #pragma unroll
    for (int k = 0; k < KW; k++) wr[k] = wl[rr][k];
    float bias = wb[(row0 + rr) & (NF-1)];
    long base = (long)(row0 + rr) * NT;
    #pragma unroll
    for (int pass = 0; pass < 3; pass++) {
      int c = cl + pass*128;
      if (c < 375) {
        int t0 = c*4;
        fx4 win[9];
        #pragma unroll
        for (int i = 0; i < 9; i++) win[i] = *(const fx4*)&z[rr][t0 + 4*i];
        float acc0 = bias, acc1 = bias, acc2 = bias, acc3 = bias;
        #pragma unroll
        for (int k = 0; k < KW; k++) {
          float wk = wr[k];
          acc0 += win[(k+1)>>2][(k+1)&3] * wk;
          acc1 += win[(k+2)>>2][(k+2)&3] * wk;
          acc2 += win[(k+3)>>2][(k+3)&3] * wk;
          acc3 += win[(k+4)>>2][(k+4)&3] * wk;
        }
        fx4 o = {acc0, acc1, acc2, acc3};
        #pragma unroll
        for (int j = 0; j < 4; j++) am = fmaxf(am, fabsf(o[j]));
        *(fx4*)&y[base + t0] = o;
      }
    }
  }
  block_amax(am, amaxY);
}

// ---------- BN stats partial: exact integer sums + biased qmin/qmax, atomics ----
__global__ void bnstats_part_k(const float* __restrict__ y, const float* amaxY,
                               int* s1a, int* s2a, unsigned* qmxa, unsigned* qmna) {
  float sy = dscale(amaxY); float inv_sy = 1.0f/sy;
  int f = blockIdx.x & 511;
  int part = blockIdx.x >> 9;          // 0..3
  int s1 = 0, s2 = 0, qmn = 127, qmx = -128;
  for (int b = part*8; b < part*8 + 8; b++) {
    const fx4* base = (const fx4*)(y + ((long)b*NF + f)*NT);
    for (int i = threadIdx.x; i < NT/4; i += blockDim.x) {
      fx4 v = base[i];
      #pragma unroll
      for (int j = 0; j < 4; j++) {
        int q = (int)fq_int(v[j], inv_sy);
        s1 += q; s2 += q*q;
        qmn = min(qmn, q); qmx = max(qmx, q);
      }
    }
  }
  #pragma unroll
  for (int o = 32; o > 0; o >>= 1) {
    s1 += __shfl_xor(s1, o); s2 += __shfl_xor(s2, o);
    qmn = min(qmn, __shfl_xor(qmn, o)); qmx = max(qmx, __shfl_xor(qmx, o));
  }
  __shared__ int rs1[4], rs2[4], rmn[4], rmx[4];
  if ((threadIdx.x & 63) == 0) {
    int wv = threadIdx.x >> 6;
    rs1[wv] = s1; rs2[wv] = s2; rmn[wv] = qmn; rmx[wv] = qmx;
  }
  __syncthreads();
  if (threadIdx.x == 0) {
    int S1 = rs1[0]+rs1[1]+rs1[2]+rs1[3];
    int S2 = rs2[0]+rs2[1]+rs2[2]+rs2[3];
    int mn = min(min(rmn[0],rmn[1]), min(rmn[2],rmn[3]));
    int mx = max(max(rmx[0],rmx[1]), max(rmx[2],rmx[3]));
    atomicAdd(s1a + f, S1);
    atomicAdd(s2a + f, S2);
    atomicMax(qmxa + f, (unsigned)(mx + 128));   // biased, init 0 safe
    atomicMax(qmna + f, (unsigned)(127 - mn));   // biased, init 0 safe
  }
}

// ---------- BN finalize: mean/rinv + EXACT amaxP via discrete sweep ----------
__global__ void bnfin_k(const int* __restrict__ s1a, const int* __restrict__ s2a,
                        const unsigned* __restrict__ qmxa, const unsigned* __restrict__ qmna,
                        const float* amaxY, const float* __restrict__ bg,
                        const float* __restrict__ bb,
                        float* bn_mean, float* bn_rinv, float* amaxP) {
  int f = blockIdx.x;
  float sy = dscale(amaxY);
  __shared__ float sh_mean, sh_rinv; __shared__ int sh_qmn, sh_qmx;
  if (threadIdx.x == 0) {
    long long S1 = s1a[f];
    long long S2 = s2a[f];
    double s = (double)sy;
    double mean = (double)S1 * s / (double)NM;
    double var  = (double)S2 * s * s / (double)NM - mean*mean;
    float fm = (float)mean;
    float fr = rsqrtf((float)var + EPSF);
    bn_mean[f] = fm; bn_rinv[f] = fr;
    sh_mean = fm; sh_rinv = fr;
    sh_qmx = (int)qmxa[f] - 128;
    sh_qmn = 127 - (int)qmna[f];
  }
  __syncthreads();
  float pm = 0.f;
  int q = sh_qmn + (int)threadIdx.x;
  if (q <= sh_qmx) {
    float zq = (float)q * sy;
    float val = (zq - sh_mean)*sh_rinv*bg[f] + bb[f];
    val = val / (1.0f + expf(-val));
    pm = fabsf(val);
  }
  block_amax(pm, amaxP);
}

// ---------- BN apply + silu + transpose + quantize + packed store (no p_raw) ----
__global__ void bnsilu_pack_k(const float* __restrict__ y, const float* __restrict__ bg,
                              const float* __restrict__ bb, const float* amaxY,
                              const float* bn_mean, const float* bn_rinv,
                              bf16* __restrict__ pq, const float* amaxP) {
  __shared__ float lds[32][33];     // [t][f]
  float sy = dscale(amaxY); float inv_sy = 1.0f/sy;
  float inv_sp = 1.0f / dscale(amaxP);
  int tx = threadIdx.x & 31, ty = threadIdx.x >> 5;
  const int TTILES = (NT + 31)/32;
  const int ntile = NB * (NF/32) * TTILES;
  for (int tile = blockIdx.x; tile < ntile; tile += gridDim.x) {
    int b = tile / ((NF/32)*TTILES);
    int rem = tile % ((NF/32)*TTILES);
    int fT = rem / TTILES, tT = rem % TTILES;
    int f0 = fT*32, t0 = tT*32;
    __syncthreads();
    #pragma unroll
    for (int sI = 0; sI < 4; sI++) {
      int f = f0 + ty + sI*8;
      int t = t0 + tx;
      if (t < NT) {
        float zq = fq_int(y[((long)b*NF + f)*NT + t], inv_sy) * sy;
        float val = (zq - bn_mean[f])*bn_rinv[f]*bg[f] + bb[f];
        val = val / (1.0f + expf(-val));
        lds[tx][ty + sI*8] = val;
      }
    }
    __syncthreads();
    if (threadIdx.x < 128) {
      int r = threadIdx.x >> 2;        // local t
      int c = threadIdx.x & 3;         // chunk of 8 f
      int t = t0 + r;
      if (t < NT) {
        bf16x8 o8;
        #pragma unroll
        for (int j = 0; j < 8; j++) o8[j] = (bf16)fq_int(lds[r][c*8 + j], inv_sp);
        long bt = (long)b*NT + t;
        int q8 = (f0 >> 3) + c;
        size_t chunk = ((size_t)(bt>>4)*16 + (q8>>2))*64 + (q8&3)*16 + (bt&15);
        ((bf16x8*)pq)[chunk] = o8;
      }
    }
  }
}

extern "C" void kernel_launch(void* const* d_in, const int* in_sizes, int n_in,
                              void* d_out, int out_size, void* d_ws, size_t ws_size,
                              hipStream_t stream) {
  const float* x  = (const float*)d_in[0];
  const float* lg = (const float*)d_in[1];
  const float* lb = (const float*)d_in[2];
  const float* W1 = (const float*)d_in[3];
  const float* b1 = (const float*)d_in[4];
  const float* dw = (const float*)d_in[5];
  const float* db = (const float*)d_in[6];
  const float* bg = (const float*)d_in[7];
  const float* bb = (const float*)d_in[8];
  const float* W2 = (const float*)d_in[9];
  const float* b2 = (const float*)d_in[10];
  float* out = (float*)d_out;

  char* ws = (char*)d_ws;
  float* amax    = (float*)ws;             // [0]=t [1]=W1 [2]=W2 [3]=dw [4]=u [5]=v [6]=y [7]=p [8]=r
  float* bn_mean = (float*)(ws + 1024);
  float* bn_rinv = (float*)(ws + 4096);
  int*      s1a  = (int*)(ws + 8192);
  int*      s2a  = (int*)(ws + 10240);
  unsigned* qmxa = (unsigned*)(ws + 12288);
  unsigned* qmna = (unsigned*)(ws + 14336);
  char* H = ws + 16384;
  float* uT    = (float*)H;                       // [0, 196.6M)  u transposed [1024][48000]
  bf16*  t_q   = (bf16*)(H + 196608000);
  float* y     = (float*)H;                       // over dead uT
  bf16*  p_q   = (bf16*)(H + 196608000);          // over dead t_q
  bf16*  W1q   = (bf16*)(H + 245760000);
  bf16*  W2q   = (bf16*)(H + 246808576);
  float* v = (float*)d_out;
  float* r = (float*)d_out;

  hipMemsetAsync(ws, 0, 16384, stream);

  absmax_w<<<392, 256, 0, stream>>>(W1, W2, dw, amax);
  quant_pack<<<256, 256, 0, stream>>>(W1, W1q, 1024, amax+1);
  quant_pack<<<128, 256, 0, stream>>>(W2, W2q, 512,  amax+2);

  ln_amax_k<<<1536, 256, 0, stream>>>(x, lg, lb, amax+0);
  ln_pack_k<<<3072, 256, 0, stream>>>(x, lg, lb, t_q, amax+0);
  gemm_k<8,0><<<3008, 256, 0, stream>>>(t_q, W1q, b1, uT, amax+0, amax+1, amax+4);
  glu_k<<<4096, 256, 0, stream>>>(uT, v, amax+4, amax+5);
  dwconv_k<<<8192, 256, 0, stream>>>(v, dw, db, y, amax+5, amax+3, amax+6);
  bnstats_part_k<<<2048, 256, 0, stream>>>(y, amax+6, s1a, s2a, qmxa, qmna);
  bnfin_k<<<512, 256, 0, stream>>>(s1a, s2a, qmxa, qmna, amax+6, bg, bb, bn_mean, bn_rinv, amax+7);
  bnsilu_pack_k<<<4096, 256, 0, stream>>>(y, bg, bb, amax+6, bn_mean, bn_rinv, p_q, amax+7);
  gemm_k<4,1><<<1504, 256, 0, stream>>>(p_q, W2q, b2, r, amax+7, amax+2, amax+8);
  quant_deq_f32<<<2048, 256, 0, stream>>>(out, 24576000/4, amax+8);
}

// Round 10
// 591.381 us; speedup vs baseline: 1.2235x; 1.2235x over previous
//
#include <hip/hip_runtime.h>
#include <stdint.h>

typedef __bf16 bf16;
typedef float    fx4    __attribute__((ext_vector_type(4)));
typedef int      ix2    __attribute__((ext_vector_type(2)));
typedef int      ix4    __attribute__((ext_vector_type(4)));

#define NB 32
#define NT 1500
#define NF 512
#define NM (NB*NT)      // 48000
#define KW 31
#define EPSF 1e-5f

__device__ __forceinline__ float dscale(const float* a) {
  return fmaxf(a[0] * (1.0f/127.0f), 1e-8f);
}
__device__ __forceinline__ float fq_int(float x, float inv_s) {
  return fminf(fmaxf(rintf(x*inv_s), -128.0f), 127.0f);
}
__device__ __forceinline__ void block_amax(float v, float* dst) {
  __shared__ float red[8];
  #pragma unroll
  for (int o = 32; o > 0; o >>= 1) v = fmaxf(v, __shfl_xor(v, o));
  if ((threadIdx.x & 63) == 0) red[threadIdx.x >> 6] = v;
  __syncthreads();
  if (threadIdx.x == 0) {
    int nw = blockDim.x >> 6;
    float m = red[0];
    for (int i = 1; i < nw; i++) m = fmaxf(m, red[i]);
    atomicMax((unsigned int*)dst, __float_as_uint(m));
  }
}

__device__ __forceinline__ float amax_loop(const float* p, long n4, int bid, int gsz) {
  float am = 0.f;
  long i = (long)bid * blockDim.x + threadIdx.x;
  long stride = (long)gsz * blockDim.x;
  for (; i < n4; i += stride) {
    fx4 v = ((const fx4*)p)[i];
    #pragma unroll
    for (int j = 0; j < 4; j++) am = fmaxf(am, fabsf(v[j]));
  }
  return am;
}
// ---------- merged weight absmax (W1, W2, dw) ----------
__global__ void absmax_w(const float* __restrict__ W1, const float* __restrict__ W2,
                         const float* __restrict__ dwp, float* a) {
  int bx = blockIdx.x;
  float am; float* dst;
  if (bx < 256)      { am = amax_loop(W1,  131072, bx,       256); dst = a + 1; }
  else if (bx < 384) { am = amax_loop(W2,  65536,  bx - 256, 128); dst = a + 2; }
  else               { am = amax_loop(dwp, 3968,   bx - 384, 8);   dst = a + 3; }
  block_amax(am, dst);
}

// ---------- quantize fp32 [R x 512] -> int8 in MFMA-i8-panel layout ----------
// Panel (r16, kb64) = 16 rows x 64 k = 1KB: chunk c = quad16*16 + m16 holds
// row m16, cols kb64*64 + quad16*16 .. +15 (16 bytes). A wave's fragment load
// (lane*16B) then covers row lane&15, k-base (lane>>4)*16 -- i8 16x16x64 layout.
__global__ void quant_pack_i8(const float* __restrict__ src, char* __restrict__ dst,
                              int R, const float* amax) {
  float inv_s = 1.0f / dscale(amax);
  int total = R * 32;                       // one thread per 16-elem chunk
  for (int t = blockIdx.x*blockDim.x + threadIdx.x; t < total; t += gridDim.x*blockDim.x) {
    int r = t >> 5, q16 = t & 31;           // read coalesced: row r, cols q16*16..+15
    const float* s = src + (size_t)r*512 + q16*16;
    ix4 o;
    #pragma unroll
    for (int g = 0; g < 4; g++) {
      fx4 v = *(const fx4*)(s + g*4);
      int wrd = 0;
      #pragma unroll
      for (int j = 0; j < 4; j++) wrd |= ((int)fq_int(v[j], inv_s) & 0xff) << (8*j);
      o[g] = wrd;
    }
    int r16 = r >> 4, m16 = r & 15, kb = q16 >> 2, quad = q16 & 3;
    size_t chunk = ((size_t)r16*8 + kb)*64 + quad*16 + m16;
    ((ix4*)dst)[chunk] = o;
  }
}

// ---------- final fake-quant fp32 in place ----------
__global__ void quant_deq_f32(float* __restrict__ p, long n4, const float* amax) {
  float s = dscale(amax);
  float inv_s = 1.0f / s;
  long i = (long)blockIdx.x * blockDim.x + threadIdx.x;
  long stride = (long)gridDim.x * blockDim.x;
  for (; i < n4; i += stride) {
    fx4 v = ((fx4*)p)[i];
    fx4 o;
    #pragma unroll
    for (int j = 0; j < 4; j++) o[j] = fq_int(v[j], inv_s) * s;
    ((fx4*)p)[i] = o;
  }
}

// ---------- LayerNorm pass 1: amax only (no stores) ----------
__global__ void ln_amax_k(const float* __restrict__ x, const float* __restrict__ g,
                          const float* __restrict__ be, float* amax) {
  int lane = threadIdx.x & 63;
  int wavesTotal = (gridDim.x * blockDim.x) >> 6;
  int wave = ((blockIdx.x * blockDim.x) + threadIdx.x) >> 6;
  fx4 g0 = ((const fx4*)g)[2*lane],  g1 = ((const fx4*)g)[2*lane+1];
  fx4 b0 = ((const fx4*)be)[2*lane], b1v = ((const fx4*)be)[2*lane+1];
  float gf[8], bff[8];
  #pragma unroll
  for (int j = 0; j < 4; j++) { gf[j] = g0[j]; gf[4+j] = g1[j]; bff[j] = b0[j]; bff[4+j] = b1v[j]; }
  float am = 0.f;
  for (int row = wave; row < NM; row += wavesTotal) {
    const fx4* xr = (const fx4*)(x + (long)row*NF);
    fx4 x0 = xr[2*lane], x1 = xr[2*lane+1];
    float xf[8]; float s = 0.f;
    #pragma unroll
    for (int j = 0; j < 4; j++) { xf[j] = x0[j]; xf[4+j] = x1[j]; }
    #pragma unroll
    for (int j = 0; j < 8; j++) s += xf[j];
    #pragma unroll
    for (int o = 32; o > 0; o >>= 1) s += __shfl_xor(s, o);
    float mu = s * (1.0f/NF);
    float vs = 0.f;
    #pragma unroll
    for (int j = 0; j < 8; j++) { float d = xf[j]-mu; vs += d*d; }
    #pragma unroll
    for (int o = 32; o > 0; o >>= 1) vs += __shfl_xor(vs, o);
    float inv = rsqrtf(vs*(1.0f/NF) + EPSF);
    #pragma unroll
    for (int j = 0; j < 8; j++) {
      float v = (xf[j]-mu)*inv*gf[j] + bff[j];
      am = fmaxf(am, fabsf(v));
    }
  }
  block_amax(am, amax);
}

// ---------- LayerNorm pass 2: recompute + quantize + packed i8 store ----------
// Lane covers cols 8l..8l+7 -> 8-byte half-chunk: kb64=l>>3, quad16=(l>>1)&3, half=l&1.
__global__ void ln_pack_k(const float* __restrict__ x, const float* __restrict__ g,
                          const float* __restrict__ be, char* __restrict__ dst,
                          const float* amax) {
  int lane = threadIdx.x & 63;
  int wavesTotal = (gridDim.x * blockDim.x) >> 6;
  int wave = ((blockIdx.x * blockDim.x) + threadIdx.x) >> 6;
  float inv_s = 1.0f / dscale(amax);
  fx4 g0 = ((const fx4*)g)[2*lane],  g1 = ((const fx4*)g)[2*lane+1];
  fx4 b0 = ((const fx4*)be)[2*lane], b1v = ((const fx4*)be)[2*lane+1];
  float gf[8], bff[8];
  #pragma unroll
  for (int j = 0; j < 4; j++) { gf[j] = g0[j]; gf[4+j] = g1[j]; bff[j] = b0[j]; bff[4+j] = b1v[j]; }
  for (int row = wave; row < NM; row += wavesTotal) {
    const fx4* xr = (const fx4*)(x + (long)row*NF);
    fx4 x0 = xr[2*lane], x1 = xr[2*lane+1];
    float xf[8]; float s = 0.f;
    #pragma unroll
    for (int j = 0; j < 4; j++) { xf[j] = x0[j]; xf[4+j] = x1[j]; }
    #pragma unroll
    for (int j = 0; j < 8; j++) s += xf[j];
    #pragma unroll
    for (int o = 32; o > 0; o >>= 1) s += __shfl_xor(s, o);
    float mu = s * (1.0f/NF);
    float vs = 0.f;
    #pragma unroll
    for (int j = 0; j < 8; j++) { float d = xf[j]-mu; vs += d*d; }
    #pragma unroll
    for (int o = 32; o > 0; o >>= 1) vs += __shfl_xor(vs, o);
    float inv = rsqrtf(vs*(1.0f/NF) + EPSF);
    int lo = 0, hi = 0;
    #pragma unroll
    for (int j = 0; j < 4; j++) {
      float v = (xf[j]-mu)*inv*gf[j] + bff[j];
      lo |= ((int)fq_int(v, inv_s) & 0xff) << (8*j);
    }
    #pragma unroll
    for (int j = 0; j < 4; j++) {
      float v = (xf[4+j]-mu)*inv*gf[4+j] + bff[4+j];
      hi |= ((int)fq_int(v, inv_s) & 0xff) << (8*j);
    }
    size_t chunk = ((size_t)(row>>4)*8 + (lane>>3))*64 + ((lane>>1)&3)*16 + (row&15);
    *(ix2*)(dst + chunk*16 + (lane&1)*8) = ix2{lo, hi};
  }
}

// ---------- MFMA i8 GEMM: direct global fragment loads, 8 K-steps of K=64 ----------
// Exact int32 accumulation; epilogue scales by st*sw. LDS-transpose epilogue:
// each store = 2 output rows x 512B contiguous.
// MODE 0: output C^T[N][M].  MODE 1: swapped mfma -> row-major C[M][N].
template<int NBN, int MODE>   // N = NBN*128
__global__ __launch_bounds__(256) void gemm_k(
    const char* __restrict__ A, const char* __restrict__ Bt,
    const float* __restrict__ bias, float* __restrict__ C,
    const float* amaxA, const float* amaxB, float* amaxC) {
  const int N = NBN * 128;
  int id = blockIdx.x;
  int bn = (id >> 3) % NBN;
  int bm = 8 * (id / (8 * NBN)) + (id & 7);
  if (bm >= 375) return;
  int lane = threadIdx.x & 63;
  int w = threadIdx.x >> 6;
  int wm = w >> 1, wn = w & 1;
  int quad = lane >> 4;
  int m16 = lane & 15;

  __shared__ __align__(16) float ebuf[2][32][132];

  ix4 acc[4][4];
  #pragma unroll
  for (int i = 0; i < 4; i++)
    #pragma unroll
    for (int j = 0; j < 4; j++) acc[i][j] = ix4{0,0,0,0};

  const char* pA[4];
  const char* pB[4];
  #pragma unroll
  for (int i = 0; i < 4; i++)
    pA[i] = A + (size_t)(bm*8 + wm*4 + i)*8192 + lane*16;   // 16-row group = 8KB
  #pragma unroll
  for (int j = 0; j < 4; j++)
    pB[j] = Bt + (size_t)(bn*8 + wn*4 + j)*8192 + lane*16;

  #pragma unroll
  for (int kb = 0; kb < 8; kb++) {
    ix4 aF[4], bF[4];
    #pragma unroll
    for (int i = 0; i < 4; i++) aF[i] = *(const ix4*)(pA[i] + kb*1024);
    #pragma unroll
    for (int j = 0; j < 4; j++) bF[j] = *(const ix4*)(pB[j] + kb*1024);
    #pragma unroll
    for (int i = 0; i < 4; i++)
      #pragma unroll
      for (int j = 0; j < 4; j++) {
        if (MODE == 0)
          acc[i][j] = __builtin_amdgcn_mfma_i32_16x16x64_i8(aF[i], bF[j], acc[i][j], 0, 0, 0);
        else
          acc[i][j] = __builtin_amdgcn_mfma_i32_16x16x64_i8(bF[j], aF[i], acc[i][j], 0, 0, 0);
      }
  }

  float ab = dscale(amaxA) * dscale(amaxB);
  float am = 0.f;
  // which half-buffer this wave fills; which 16-row slice it drains
  const int h     = (MODE == 0) ? wn : wm;
  const int other = (MODE == 0) ? wm : wn;

  #pragma unroll
  for (int rnd = 0; rnd < 2; rnd++) {
    __syncthreads();                 // prev round's reads done before overwrite
    if (MODE == 0) {
      // out-row = N col; within = M. acc[i][j]: col=wn*64+j*16+m16, m=wm*64+i*16+quad*4
      #pragma unroll
      for (int jj = 0; jj < 2; jj++) {
        int j = rnd*2 + jj;
        int col = bn*128 + wn*64 + j*16 + m16;
        float bv = bias[col];
        #pragma unroll
        for (int i = 0; i < 4; i++) {
          fx4 o;
          #pragma unroll
          for (int rr = 0; rr < 4; rr++) {
            float v = (float)acc[i][j][rr]*ab + bv;
            am = fmaxf(am, fabsf(v)); o[rr] = v;
          }
          *(fx4*)&ebuf[h][jj*16 + m16][wm*64 + i*16 + quad*4] = o;
        }
      }
    } else {
      // out-row = M; within = N. acc[i][j]: m=wm*64+i*16+m16, n=wn*64+j*16+quad*4
      #pragma unroll
      for (int ii = 0; ii < 2; ii++) {
        int i = rnd*2 + ii;
        #pragma unroll
        for (int j = 0; j < 4; j++) {
          int n0 = bn*128 + wn*64 + j*16 + quad*4;
          fx4 bv = *(const fx4*)(bias + n0);
          fx4 o;
          #pragma unroll
          for (int rr = 0; rr < 4; rr++) {
            float v = (float)acc[i][j][rr]*ab + bv[rr];
            am = fmaxf(am, fabsf(v)); o[rr] = v;
          }
          *(fx4*)&ebuf[h][ii*16 + m16][wn*64 + j*16 + quad*4] = o;
        }
      }
    }
    __syncthreads();
    // drain: wave reads its 16-row slice of buffer h, 2 rows x 512B per store
    #pragma unroll
    for (int it = 0; it < 8; it++) {
      int lrow = other*16 + it*2 + (lane >> 5);
      int cf = (lane & 31) * 4;
      fx4 o = *(const fx4*)&ebuf[h][lrow][cf];
      int orow = ((MODE == 0) ? bn*128 : bm*128) + h*64 + rnd*32 + lrow;
      size_t base = (MODE == 0) ? ((size_t)orow*NM + (size_t)bm*128 + cf)
                                : ((size_t)orow*N  + (size_t)bn*128 + cf);
      *(fx4*)(C + base) = o;
    }
  }
  block_amax(am, amaxC);
}

// ---------- GLU from uT [1024][48000] -> v[B,F,T], pure streaming ----------
__global__ void glu_k(const float* __restrict__ uT, float* __restrict__ v,
                      const float* amaxU, float* amaxV) {
  float s = dscale(amaxU);
  float inv_s = 1.0f / s;
  float am = 0.f;
  const int tid = threadIdx.x;
  const int npairs = (NB*NF)/2;     // 8192 pairs of (b,f) rows
  for (int pr = blockIdx.x; pr < npairs; pr += gridDim.x) {
    int row0 = pr*2;
    for (int i = tid; i < 750; i += 256) {
      int r2 = (i >= 375) ? 1 : 0;
      int c = i - 375*r2;
      int row = row0 + r2;                 // row = b*NF + f
      int b = row >> 9, f = row & (NF-1);
      long bt = (long)b*NT + c*4;
      fx4 a = *(const fx4*)(uT + (long)f*NM + bt);
      fx4 g = *(const fx4*)(uT + (long)(f+NF)*NM + bt);
      fx4 o;
      #pragma unroll
      for (int j = 0; j < 4; j++) {
        float av = fq_int(a[j], inv_s) * s;
        float gv = fq_int(g[j], inv_s) * s;
        float val = av * (1.0f/(1.0f + expf(-gv)));
        am = fmaxf(am, fabsf(val));
        o[j] = val;
      }
      *(fx4*)(v + (long)row*NT + c*4) = o;
    }
  }
  block_amax(am, amaxV);
}

// ---------- depthwise conv K=31 on [B,F,T] ----------
__global__ void dwconv_k(const float* __restrict__ v, const float* __restrict__ w,
                         const float* __restrict__ wb, float* __restrict__ y,
                         const float* amaxV, const float* amaxW, float* amaxY) {
  __shared__ float z[2][1568];     // [row][16 left pad + 1500 + right pad]
  __shared__ float wl[2][32];
  float sv = dscale(amaxV); float inv_sv = 1.0f/sv;
  float sw = dscale(amaxW); float inv_sw = 1.0f/sw;
  float am = 0.f;
  const int tid = threadIdx.x;
  const int rr = tid >> 7;          // which row of the pair this thread computes
  const int cl = tid & 127;         // chunk lane within the half
  const int npairs = (NB*NF)/2;     // 8192
  for (int pr = blockIdx.x; pr < npairs; pr += gridDim.x) {
    int row0 = pr*2;
    __syncthreads();
    if (tid < 64) {
      int r2 = tid >> 5, k = tid & 31;
      if (k < KW) {
        int f = (row0 + r2) & (NF-1);
        wl[r2][k] = fq_int(w[f*KW + k], inv_sw) * sw;
      }
    }
    if (tid < 128) {
      int r2 = tid >> 6, jj = tid & 63;
      if (jj < 16) z[r2][jj] = 0.f;
      else         z[r2][1500 + jj] = 0.f;
    }
    const fx4* vp = (const fx4*)(v + (long)row0 * NT);
    for (int i = tid; i < 750; i += 256) {
      fx4 q = vp[i];
      int r2 = (i >= 375) ? 1 : 0;
      int ii = i - 375*r2;
      fx4 o;
      #pragma unroll
      for (int j = 0; j < 4; j++) o[j] = fq_int(q[j], inv_sv) * sv;
      *(fx4*)&z[r2][16 + 4*ii] = o;
    }
    __syncthreads();
    float wr[KW];
    #pragma unroll
    for (int k = 0; k < KW; k++) wr[k] = wl[rr][k];
    float bias = wb[(row0 + rr) & (NF-1)];
    long base = (long)(row0 + rr) * NT;
    #pragma unroll
    for (int pass = 0; pass < 3; pass++) {
      int c = cl + pass*128;
      if (c < 375) {
        int t0 = c*4;
        fx4 win[9];
        #pragma unroll
        for (int i = 0; i < 9; i++) win[i] = *(const fx4*)&z[rr][t0 + 4*i];
        float acc0 = bias, acc1 = bias, acc2 = bias, acc3 = bias;
        #pragma unroll
        for (int k = 0; k < KW; k++) {
          float wk = wr[k];
          acc0 += win[(k+1)>>2][(k+1)&3] * wk;
          acc1 += win[(k+2)>>2][(k+2)&3] * wk;
          acc2 += win[(k+3)>>2][(k+3)&3] * wk;
          acc3 += win[(k+4)>>2][(k+4)&3] * wk;
        }
        fx4 o = {acc0, acc1, acc2, acc3};
        #pragma unroll
        for (int j = 0; j < 4; j++) am = fmaxf(am, fabsf(o[j]));
        *(fx4*)&y[base + t0] = o;
      }
    }
  }
  block_amax(am, amaxY);
}

// ---------- BN stats partial: exact integer sums + biased qmin/qmax, atomics ----
__global__ void bnstats_part_k(const float* __restrict__ y, const float* amaxY,
                               int* s1a, int* s2a, unsigned* qmxa, unsigned* qmna) {
  float sy = dscale(amaxY); float inv_sy = 1.0f/sy;
  int f = blockIdx.x & 511;
  int part = blockIdx.x >> 9;          // 0..3
  int s1 = 0, s2 = 0, qmn = 127, qmx = -128;
  for (int b = part*8; b < part*8 + 8; b++) {
    const fx4* base = (const fx4*)(y + ((long)b*NF + f)*NT);
    for (int i = threadIdx.x; i < NT/4; i += blockDim.x) {
      fx4 v = base[i];
      #pragma unroll
      for (int j = 0; j < 4; j++) {
        int q = (int)fq_int(v[j], inv_sy);
        s1 += q; s2 += q*q;
        qmn = min(qmn, q); qmx = max(qmx, q);
      }
    }
  }
  #pragma unroll
  for (int o = 32; o > 0; o >>= 1) {
    s1 += __shfl_xor(s1, o); s2 += __shfl_xor(s2, o);
    qmn = min(qmn, __shfl_xor(qmn, o)); qmx = max(qmx, __shfl_xor(qmx, o));
  }
  __shared__ int rs1[4], rs2[4], rmn[4], rmx[4];
  if ((threadIdx.x & 63) == 0) {
    int wv = threadIdx.x >> 6;
    rs1[wv] = s1; rs2[wv] = s2; rmn[wv] = qmn; rmx[wv] = qmx;
  }
  __syncthreads();
  if (threadIdx.x == 0) {
    int S1 = rs1[0]+rs1[1]+rs1[2]+rs1[3];
    int S2 = rs2[0]+rs2[1]+rs2[2]+rs2[3];
    int mn = min(min(rmn[0],rmn[1]), min(rmn[2],rmn[3]));
    int mx = max(max(rmx[0],rmx[1]), max(rmx[2],rmx[3]));
    atomicAdd(s1a + f, S1);
    atomicAdd(s2a + f, S2);
    atomicMax(qmxa + f, (unsigned)(mx + 128));   // biased, init 0 safe
    atomicMax(qmna + f, (unsigned)(127 - mn));   // biased, init 0 safe
  }
}

// ---------- BN finalize: mean/rinv + EXACT amaxP via discrete sweep ----------
__global__ void bnfin_k(const int* __restrict__ s1a, const int* __restrict__ s2a,
                        const unsigned* __restrict__ qmxa, const unsigned* __restrict__ qmna,
                        const float* amaxY, const float* __restrict__ bg,
                        const float* __restrict__ bb,
                        float* bn_mean, float* bn_rinv, float* amaxP) {
  int f = blockIdx.x;
  float sy = dscale(amaxY);
  __shared__ float sh_mean, sh_rinv; __shared__ int sh_qmn, sh_qmx;
  if (threadIdx.x == 0) {
    long long S1 = s1a[f];
    long long S2 = s2a[f];
    double s = (double)sy;
    double mean = (double)S1 * s / (double)NM;
    double var  = (double)S2 * s * s / (double)NM - mean*mean;
    float fm = (float)mean;
    float fr = rsqrtf((float)var + EPSF);
    bn_mean[f] = fm; bn_rinv[f] = fr;
    sh_mean = fm; sh_rinv = fr;
    sh_qmx = (int)qmxa[f] - 128;
    sh_qmn = 127 - (int)qmna[f];
  }
  __syncthreads();
  float pm = 0.f;
  int q = sh_qmn + (int)threadIdx.x;
  if (q <= sh_qmx) {
    float zq = (float)q * sy;
    float val = (zq - sh_mean)*sh_rinv*bg[f] + bb[f];
    val = val / (1.0f + expf(-val));
    pm = fabsf(val);
  }
  block_amax(pm, amaxP);
}

// ---------- BN apply + silu + transpose + quantize + packed i8 store ----------
__global__ void bnsilu_pack_k(const float* __restrict__ y, const float* __restrict__ bg,
                              const float* __restrict__ bb, const float* amaxY,
                              const float* bn_mean, const float* bn_rinv,
                              char* __restrict__ pq, const float* amaxP) {
  __shared__ float lds[32][33];     // [t][f]
  float sy = dscale(amaxY); float inv_sy = 1.0f/sy;
  float inv_sp = 1.0f / dscale(amaxP);
  int tx = threadIdx.x & 31, ty = threadIdx.x >> 5;
  const int TTILES = (NT + 31)/32;
  const int ntile = NB * (NF/32) * TTILES;
  for (int tile = blockIdx.x; tile < ntile; tile += gridDim.x) {
    int b = tile / ((NF/32)*TTILES);
    int rem = tile % ((NF/32)*TTILES);
    int fT = rem / TTILES, tT = rem % TTILES;
    int f0 = fT*32, t0 = tT*32;
    __syncthreads();
    #pragma unroll
    for (int sI = 0; sI < 4; sI++) {
      int f = f0 + ty + sI*8;
      int t = t0 + tx;
      if (t < NT) {
        float zq = fq_int(y[((long)b*NF + f)*NT + t], inv_sy) * sy;
        float val = (zq - bn_mean[f])*bn_rinv[f]*bg[f] + bb[f];
        val = val / (1.0f + expf(-val));
        lds[tx][ty + sI*8] = val;
      }
    }
    __syncthreads();
    if (threadIdx.x < 128) {
      int r = threadIdx.x >> 2;        // local t
      int c = threadIdx.x & 3;         // 8-col group within the 32-f tile
      int t = t0 + r;
      if (t < NT) {
        int lo = 0, hi = 0;
        #pragma unroll
        for (int j = 0; j < 4; j++)
          lo |= ((int)fq_int(lds[r][c*8 + j],     inv_sp) & 0xff) << (8*j);
        #pragma unroll
        for (int j = 0; j < 4; j++)
          hi |= ((int)fq_int(lds[r][c*8 + 4 + j], inv_sp) & 0xff) << (8*j);
        long bt = (long)b*NT + t;
        int q8 = (f0 >> 3) + c;          // global 8-col group, 0..63
        size_t chunk = ((size_t)(bt>>4)*8 + (q8>>3))*64 + ((q8>>1)&3)*16 + (bt&15);
        *(ix2*)(pq + chunk*16 + (q8&1)*8) = ix2{lo, hi};
      }
    }
  }
}

extern "C" void kernel_launch(void* const* d_in, const int* in_sizes, int n_in,
                              void* d_out, int out_size, void* d_ws, size_t ws_size,
                              hipStream_t stream) {
  const float* x  = (const float*)d_in[0];
  const float* lg = (const float*)d_in[1];
  const float* lb = (const float*)d_in[2];
  const float* W1 = (const float*)d_in[3];
  const float* b1 = (const float*)d_in[4];
  const float* dw = (const float*)d_in[5];
  const float* db = (const float*)d_in[6];
  const float* bg = (const float*)d_in[7];
  const float* bb = (const float*)d_in[8];
  const float* W2 = (const float*)d_in[9];
  const float* b2 = (const float*)d_in[10];
  float* out = (float*)d_out;

  char* ws = (char*)d_ws;
  float* amax    = (float*)ws;             // [0]=t [1]=W1 [2]=W2 [3]=dw [4]=u [5]=v [6]=y [7]=p [8]=r
  float* bn_mean = (float*)(ws + 1024);
  float* bn_rinv = (float*)(ws + 4096);
  int*      s1a  = (int*)(ws + 8192);
  int*      s2a  = (int*)(ws + 10240);
  unsigned* qmxa = (unsigned*)(ws + 12288);
  unsigned* qmna = (unsigned*)(ws + 14336);
  char* H = ws + 16384;
  float* uT    = (float*)H;                       // [0, 196.6M)  u transposed [1024][48000]
  char*  t_q   = H + 196608000;                   // 24.576 MB i8 packed
  float* y     = (float*)H;                       // over dead uT
  char*  p_q   = H + 221184000;                   // 24.576 MB i8 packed
  char*  W1q   = H + 245760000;                   // 512 KB
  char*  W2q   = H + 246284288;                   // 256 KB
  float* v = (float*)d_out;
  float* r = (float*)d_out;

  hipMemsetAsync(ws, 0, 16384, stream);

  absmax_w<<<392, 256, 0, stream>>>(W1, W2, dw, amax);
  quant_pack_i8<<<128, 256, 0, stream>>>(W1, W1q, 1024, amax+1);
  quant_pack_i8<<<64,  256, 0, stream>>>(W2, W2q, 512,  amax+2);

  ln_amax_k<<<1536, 256, 0, stream>>>(x, lg, lb, amax+0);
  ln_pack_k<<<3072, 256, 0, stream>>>(x, lg, lb, t_q, amax+0);
  gemm_k<8,0><<<3008, 256, 0, stream>>>(t_q, W1q, b1, uT, amax+0, amax+1, amax+4);
  glu_k<<<4096, 256, 0, stream>>>(uT, v, amax+4, amax+5);
  dwconv_k<<<8192, 256, 0, stream>>>(v, dw, db, y, amax+5, amax+3, amax+6);
  bnstats_part_k<<<2048, 256, 0, stream>>>(y, amax+6, s1a, s2a, qmxa, qmna);
  bnfin_k<<<512, 256, 0, stream>>>(s1a, s2a, qmxa, qmna, amax+6, bg, bb, bn_mean, bn_rinv, amax+7);
  bnsilu_pack_k<<<4096, 256, 0, stream>>>(y, bg, bb, amax+6, bn_mean, bn_rinv, p_q, amax+7);
  gemm_k<4,1><<<1504, 256, 0, stream>>>(p_q, W2q, b2, r, amax+7, amax+2, amax+8);
  quant_deq_f32<<<2048, 256, 0, stream>>>(out, 24576000/4, amax+8);
}

// Round 11
// 548.713 us; speedup vs baseline: 1.3187x; 1.0778x over previous
//
#include <hip/hip_runtime.h>
#include <stdint.h>

typedef __bf16 bf16;
typedef float    fx4    __attribute__((ext_vector_type(4)));
typedef int      ix2    __attribute__((ext_vector_type(2)));
typedef int      ix4    __attribute__((ext_vector_type(4)));

#define NB 32
#define NT 1500
#define NF 512
#define NM (NB*NT)      // 48000
#define KW 31
#define EPSF 1e-5f

__device__ __forceinline__ float dscale(const float* a) {
  return fmaxf(a[0] * (1.0f/127.0f), 1e-8f);
}
__device__ __forceinline__ float fq_int(float x, float inv_s) {
  return fminf(fmaxf(rintf(x*inv_s), -128.0f), 127.0f);
}
__device__ __forceinline__ void block_amax(float v, float* dst) {
  __shared__ float red[8];
  #pragma unroll
  for (int o = 32; o > 0; o >>= 1) v = fmaxf(v, __shfl_xor(v, o));
  if ((threadIdx.x & 63) == 0) red[threadIdx.x >> 6] = v;
  __syncthreads();
  if (threadIdx.x == 0) {
    int nw = blockDim.x >> 6;
    float m = red[0];
    for (int i = 1; i < nw; i++) m = fmaxf(m, red[i]);
    atomicMax((unsigned int*)dst, __float_as_uint(m));
  }
}

__device__ __forceinline__ float amax_loop(const float* p, long n4, int bid, int gsz) {
  float am = 0.f;
  long i = (long)bid * blockDim.x + threadIdx.x;
  long stride = (long)gsz * blockDim.x;
  for (; i < n4; i += stride) {
    fx4 v = ((const fx4*)p)[i];
    #pragma unroll
    for (int j = 0; j < 4; j++) am = fmaxf(am, fabsf(v[j]));
  }
  return am;
}
// ---------- merged weight absmax (W1, W2, dw) ----------
__global__ void absmax_w(const float* __restrict__ W1, const float* __restrict__ W2,
                         const float* __restrict__ dwp, float* a) {
  int bx = blockIdx.x;
  float am; float* dst;
  if (bx < 256)      { am = amax_loop(W1,  131072, bx,       256); dst = a + 1; }
  else if (bx < 384) { am = amax_loop(W2,  65536,  bx - 256, 128); dst = a + 2; }
  else               { am = amax_loop(dwp, 3968,   bx - 384, 8);   dst = a + 3; }
  block_amax(am, dst);
}

// ---------- quantize fp32 [R x 512] -> int8 in MFMA-i8-panel layout ----------
__global__ void quant_pack_i8(const float* __restrict__ src, char* __restrict__ dst,
                              int R, const float* amax) {
  float inv_s = 1.0f / dscale(amax);
  int total = R * 32;                       // one thread per 16-elem chunk
  for (int t = blockIdx.x*blockDim.x + threadIdx.x; t < total; t += gridDim.x*blockDim.x) {
    int r = t >> 5, q16 = t & 31;           // read coalesced: row r, cols q16*16..+15
    const float* s = src + (size_t)r*512 + q16*16;
    ix4 o;
    #pragma unroll
    for (int g = 0; g < 4; g++) {
      fx4 v = *(const fx4*)(s + g*4);
      int wrd = 0;
      #pragma unroll
      for (int j = 0; j < 4; j++) wrd |= ((int)fq_int(v[j], inv_s) & 0xff) << (8*j);
      o[g] = wrd;
    }
    int r16 = r >> 4, m16 = r & 15, kb = q16 >> 2, quad = q16 & 3;
    size_t chunk = ((size_t)r16*8 + kb)*64 + quad*16 + m16;
    ((ix4*)dst)[chunk] = o;
  }
}

// ---------- final fake-quant fp32 in place ----------
__global__ void quant_deq_f32(float* __restrict__ p, long n4, const float* amax) {
  float s = dscale(amax);
  float inv_s = 1.0f / s;
  long i = (long)blockIdx.x * blockDim.x + threadIdx.x;
  long stride = (long)gridDim.x * blockDim.x;
  for (; i < n4; i += stride) {
    fx4 v = ((fx4*)p)[i];
    fx4 o;
    #pragma unroll
    for (int j = 0; j < 4; j++) o[j] = fq_int(v[j], inv_s) * s;
    ((fx4*)p)[i] = o;
  }
}

// ---------- LayerNorm pass 1: amax only (no stores) ----------
__global__ void ln_amax_k(const float* __restrict__ x, const float* __restrict__ g,
                          const float* __restrict__ be, float* amax) {
  int lane = threadIdx.x & 63;
  int wavesTotal = (gridDim.x * blockDim.x) >> 6;
  int wave = ((blockIdx.x * blockDim.x) + threadIdx.x) >> 6;
  fx4 g0 = ((const fx4*)g)[2*lane],  g1 = ((const fx4*)g)[2*lane+1];
  fx4 b0 = ((const fx4*)be)[2*lane], b1v = ((const fx4*)be)[2*lane+1];
  float gf[8], bff[8];
  #pragma unroll
  for (int j = 0; j < 4; j++) { gf[j] = g0[j]; gf[4+j] = g1[j]; bff[j] = b0[j]; bff[4+j] = b1v[j]; }
  float am = 0.f;
  for (int row = wave; row < NM; row += wavesTotal) {
    const fx4* xr = (const fx4*)(x + (long)row*NF);
    fx4 x0 = xr[2*lane], x1 = xr[2*lane+1];
    float xf[8]; float s = 0.f;
    #pragma unroll
    for (int j = 0; j < 4; j++) { xf[j] = x0[j]; xf[4+j] = x1[j]; }
    #pragma unroll
    for (int j = 0; j < 8; j++) s += xf[j];
    #pragma unroll
    for (int o = 32; o > 0; o >>= 1) s += __shfl_xor(s, o);
    float mu = s * (1.0f/NF);
    float vs = 0.f;
    #pragma unroll
    for (int j = 0; j < 8; j++) { float d = xf[j]-mu; vs += d*d; }
    #pragma unroll
    for (int o = 32; o > 0; o >>= 1) vs += __shfl_xor(vs, o);
    float inv = rsqrtf(vs*(1.0f/NF) + EPSF);
    #pragma unroll
    for (int j = 0; j < 8; j++) {
      float v = (xf[j]-mu)*inv*gf[j] + bff[j];
      am = fmaxf(am, fabsf(v));
    }
  }
  block_amax(am, amax);
}

// ---------- LayerNorm pass 2: recompute + quantize + packed i8 store ----------
__global__ void ln_pack_k(const float* __restrict__ x, const float* __restrict__ g,
                          const float* __restrict__ be, char* __restrict__ dst,
                          const float* amax) {
  int lane = threadIdx.x & 63;
  int wavesTotal = (gridDim.x * blockDim.x) >> 6;
  int wave = ((blockIdx.x * blockDim.x) + threadIdx.x) >> 6;
  float inv_s = 1.0f / dscale(amax);
  fx4 g0 = ((const fx4*)g)[2*lane],  g1 = ((const fx4*)g)[2*lane+1];
  fx4 b0 = ((const fx4*)be)[2*lane], b1v = ((const fx4*)be)[2*lane+1];
  float gf[8], bff[8];
  #pragma unroll
  for (int j = 0; j < 4; j++) { gf[j] = g0[j]; gf[4+j] = g1[j]; bff[j] = b0[j]; bff[4+j] = b1v[j]; }
  for (int row = wave; row < NM; row += wavesTotal) {
    const fx4* xr = (const fx4*)(x + (long)row*NF);
    fx4 x0 = xr[2*lane], x1 = xr[2*lane+1];
    float xf[8]; float s = 0.f;
    #pragma unroll
    for (int j = 0; j < 4; j++) { xf[j] = x0[j]; xf[4+j] = x1[j]; }
    #pragma unroll
    for (int j = 0; j < 8; j++) s += xf[j];
    #pragma unroll
    for (int o = 32; o > 0; o >>= 1) s += __shfl_xor(s, o);
    float mu = s * (1.0f/NF);
    float vs = 0.f;
    #pragma unroll
    for (int j = 0; j < 8; j++) { float d = xf[j]-mu; vs += d*d; }
    #pragma unroll
    for (int o = 32; o > 0; o >>= 1) vs += __shfl_xor(vs, o);
    float inv = rsqrtf(vs*(1.0f/NF) + EPSF);
    int lo = 0, hi = 0;
    #pragma unroll
    for (int j = 0; j < 4; j++) {
      float v = (xf[j]-mu)*inv*gf[j] + bff[j];
      lo |= ((int)fq_int(v, inv_s) & 0xff) << (8*j);
    }
    #pragma unroll
    for (int j = 0; j < 4; j++) {
      float v = (xf[4+j]-mu)*inv*gf[4+j] + bff[4+j];
      hi |= ((int)fq_int(v, inv_s) & 0xff) << (8*j);
    }
    size_t chunk = ((size_t)(row>>4)*8 + (lane>>3))*64 + ((lane>>1)&3)*16 + (row&15);
    *(ix2*)(dst + chunk*16 + (lane&1)*8) = ix2{lo, hi};
  }
}

// ---------- MFMA i8 GEMM: direct global fragment loads, 8 K-steps of K=64 ----------
template<int NBN, int MODE>   // N = NBN*128
__global__ __launch_bounds__(256) void gemm_k(
    const char* __restrict__ A, const char* __restrict__ Bt,
    const float* __restrict__ bias, float* __restrict__ C,
    const float* amaxA, const float* amaxB, float* amaxC) {
  const int N = NBN * 128;
  int id = blockIdx.x;
  int bn = (id >> 3) % NBN;
  int bm = 8 * (id / (8 * NBN)) + (id & 7);
  if (bm >= 375) return;
  int lane = threadIdx.x & 63;
  int w = threadIdx.x >> 6;
  int wm = w >> 1, wn = w & 1;
  int quad = lane >> 4;
  int m16 = lane & 15;

  __shared__ __align__(16) float ebuf[2][32][132];

  ix4 acc[4][4];
  #pragma unroll
  for (int i = 0; i < 4; i++)
    #pragma unroll
    for (int j = 0; j < 4; j++) acc[i][j] = ix4{0,0,0,0};

  const char* pA[4];
  const char* pB[4];
  #pragma unroll
  for (int i = 0; i < 4; i++)
    pA[i] = A + (size_t)(bm*8 + wm*4 + i)*8192 + lane*16;   // 16-row group = 8KB
  #pragma unroll
  for (int j = 0; j < 4; j++)
    pB[j] = Bt + (size_t)(bn*8 + wn*4 + j)*8192 + lane*16;

  #pragma unroll
  for (int kb = 0; kb < 8; kb++) {
    ix4 aF[4], bF[4];
    #pragma unroll
    for (int i = 0; i < 4; i++) aF[i] = *(const ix4*)(pA[i] + kb*1024);
    #pragma unroll
    for (int j = 0; j < 4; j++) bF[j] = *(const ix4*)(pB[j] + kb*1024);
    #pragma unroll
    for (int i = 0; i < 4; i++)
      #pragma unroll
      for (int j = 0; j < 4; j++) {
        if (MODE == 0)
          acc[i][j] = __builtin_amdgcn_mfma_i32_16x16x64_i8(aF[i], bF[j], acc[i][j], 0, 0, 0);
        else
          acc[i][j] = __builtin_amdgcn_mfma_i32_16x16x64_i8(bF[j], aF[i], acc[i][j], 0, 0, 0);
      }
  }

  float ab = dscale(amaxA) * dscale(amaxB);
  float am = 0.f;
  // which half-buffer this wave fills; which 16-row slice it drains
  const int h     = (MODE == 0) ? wn : wm;
  const int other = (MODE == 0) ? wm : wn;

  #pragma unroll
  for (int rnd = 0; rnd < 2; rnd++) {
    __syncthreads();                 // prev round's reads done before overwrite
    if (MODE == 0) {
      // out-row = N col; within = M. acc[i][j]: col=wn*64+j*16+m16, m=wm*64+i*16+quad*4
      #pragma unroll
      for (int jj = 0; jj < 2; jj++) {
        int j = rnd*2 + jj;
        int col = bn*128 + wn*64 + j*16 + m16;
        float bv = bias[col];
        #pragma unroll
        for (int i = 0; i < 4; i++) {
          fx4 o;
          #pragma unroll
          for (int rr = 0; rr < 4; rr++) {
            float v = (float)acc[i][j][rr]*ab + bv;
            am = fmaxf(am, fabsf(v)); o[rr] = v;
          }
          *(fx4*)&ebuf[h][jj*16 + m16][wm*64 + i*16 + quad*4] = o;
        }
      }
    } else {
      // out-row = M; within = N. acc[i][j]: m=wm*64+i*16+m16, n=wn*64+j*16+quad*4
      #pragma unroll
      for (int ii = 0; ii < 2; ii++) {
        int i = rnd*2 + ii;
        #pragma unroll
        for (int j = 0; j < 4; j++) {
          int n0 = bn*128 + wn*64 + j*16 + quad*4;
          fx4 bv = *(const fx4*)(bias + n0);
          fx4 o;
          #pragma unroll
          for (int rr = 0; rr < 4; rr++) {
            float v = (float)acc[i][j][rr]*ab + bv[rr];
            am = fmaxf(am, fabsf(v)); o[rr] = v;
          }
          *(fx4*)&ebuf[h][ii*16 + m16][wn*64 + j*16 + quad*4] = o;
        }
      }
    }
    __syncthreads();
    // drain: wave reads its 16-row slice of buffer h, 2 rows x 512B per store
    #pragma unroll
    for (int it = 0; it < 8; it++) {
      int lrow = other*16 + it*2 + (lane >> 5);
      int cf = (lane & 31) * 4;
      fx4 o = *(const fx4*)&ebuf[h][lrow][cf];
      int orow = ((MODE == 0) ? bn*128 : bm*128) + h*64 + rnd*32 + lrow;
      size_t base = (MODE == 0) ? ((size_t)orow*NM + (size_t)bm*128 + cf)
                                : ((size_t)orow*N  + (size_t)bn*128 + cf);
      *(fx4*)(C + base) = o;
    }
  }
  block_amax(am, amaxC);
}

// ---------- GLU from uT [1024][48000] -> v[B,F,T], pure streaming ----------
__global__ void glu_k(const float* __restrict__ uT, float* __restrict__ v,
                      const float* amaxU, float* amaxV) {
  float s = dscale(amaxU);
  float inv_s = 1.0f / s;
  float am = 0.f;
  const int tid = threadIdx.x;
  const int npairs = (NB*NF)/2;     // 8192 pairs of (b,f) rows
  for (int pr = blockIdx.x; pr < npairs; pr += gridDim.x) {
    int row0 = pr*2;
    for (int i = tid; i < 750; i += 256) {
      int r2 = (i >= 375) ? 1 : 0;
      int c = i - 375*r2;
      int row = row0 + r2;                 // row = b*NF + f
      int b = row >> 9, f = row & (NF-1);
      long bt = (long)b*NT + c*4;
      fx4 a = *(const fx4*)(uT + (long)f*NM + bt);
      fx4 g = *(const fx4*)(uT + (long)(f+NF)*NM + bt);
      fx4 o;
      #pragma unroll
      for (int j = 0; j < 4; j++) {
        float av = fq_int(a[j], inv_s) * s;
        float gv = fq_int(g[j], inv_s) * s;
        float val = av * (1.0f/(1.0f + expf(-gv)));
        am = fmaxf(am, fabsf(val));
        o[j] = val;
      }
      *(fx4*)(v + (long)row*NT + c*4) = o;
    }
  }
  block_amax(am, amaxV);
}

// ---------- depthwise conv K=31 on [B,F,T], pipelined pairs ----------
// Grid 2048, 4 pairs per block. Pair i+1's global loads (3 fx4/thread + weights)
// are ISSUED before pair i's compute; quantize+ds_write happen after the compute
// barrier (T14 async-STAGE split) -> HBM latency hides under the FMA phase.
__global__ void dwconv_k(const float* __restrict__ v, const float* __restrict__ w,
                         const float* __restrict__ wb, float* __restrict__ y,
                         const float* amaxV, const float* amaxW, float* amaxY) {
  __shared__ float z[2][1568];     // [row][16 left pad + 1500 + right pad]
  __shared__ float wl[2][32];
  float sv = dscale(amaxV); float inv_sv = 1.0f/sv;
  float sw = dscale(amaxW); float inv_sw = 1.0f/sw;
  float am = 0.f;
  const int tid = threadIdx.x;
  const int rr = tid >> 7;          // which row of the pair this thread computes
  const int cl = tid & 127;         // chunk lane within the half
  const int wr2 = tid >> 5, wkk = tid & 31;   // weight-load role (tid < 64)

  // one-time halo zeroing: staging only writes [16, 1516)
  if (tid < 128) {
    int r2 = tid >> 6, jj = tid & 63;
    if (jj < 16) z[r2][jj] = 0.f;
    else         z[r2][1500 + jj] = 0.f;
  }

  fx4 st[3];
  float wreg = 0.f;

  // prologue: issue + stage pair blockIdx.x
  {
    long vb = (long)(blockIdx.x*2) * NT;
    #pragma unroll
    for (int k = 0; k < 3; k++) {
      int i = tid + k*256;
      if (i < 750) st[k] = *(const fx4*)(v + vb + i*4);
    }
    if (tid < 64 && wkk < KW)
      wreg = w[((blockIdx.x*2 + wr2) & (NF-1))*KW + wkk];
    #pragma unroll
    for (int k = 0; k < 3; k++) {
      int i = tid + k*256;
      if (i < 750) {
        int r2 = (i >= 375) ? 1 : 0;
        int ii = i - 375*r2;
        fx4 o;
        #pragma unroll
        for (int j = 0; j < 4; j++) o[j] = fq_int(st[k][j], inv_sv) * sv;
        *(fx4*)&z[r2][16 + 4*ii] = o;
      }
    }
    if (tid < 64 && wkk < KW) wl[wr2][wkk] = fq_int(wreg, inv_sw) * sw;
  }
  __syncthreads();

  #pragma unroll
  for (int idx = 0; idx < 4; idx++) {
    int p = blockIdx.x + idx*2048;
    // issue NEXT pair's loads early (latency hides under compute below)
    if (idx < 3) {
      long vb = (long)((p + 2048)*2) * NT;
      #pragma unroll
      for (int k = 0; k < 3; k++) {
        int i = tid + k*256;
        if (i < 750) st[k] = *(const fx4*)(v + vb + i*4);
      }
      if (tid < 64 && wkk < KW)
        wreg = w[(((p + 2048)*2 + wr2) & (NF-1))*KW + wkk];
    }
    // compute current pair from LDS
    float wr[KW];
    #pragma unroll
    for (int k = 0; k < KW; k++) wr[k] = wl[rr][k];
    float bias = wb[(p*2 + rr) & (NF-1)];
    long base = (long)(p*2 + rr) * NT;
    #pragma unroll
    for (int pass = 0; pass < 3; pass++) {
      int c = cl + pass*128;
      if (c < 375) {
        int t0 = c*4;
        fx4 win[9];
        #pragma unroll
        for (int i = 0; i < 9; i++) win[i] = *(const fx4*)&z[rr][t0 + 4*i];
        float acc0 = bias, acc1 = bias, acc2 = bias, acc3 = bias;
        #pragma unroll
        for (int k = 0; k < KW; k++) {
          float wk = wr[k];
          acc0 += win[(k+1)>>2][(k+1)&3] * wk;
          acc1 += win[(k+2)>>2][(k+2)&3] * wk;
          acc2 += win[(k+3)>>2][(k+3)&3] * wk;
          acc3 += win[(k+4)>>2][(k+4)&3] * wk;
        }
        fx4 o = {acc0, acc1, acc2, acc3};
        #pragma unroll
        for (int j = 0; j < 4; j++) am = fmaxf(am, fabsf(o[j]));
        *(fx4*)&y[base + t0] = o;
      }
    }
    __syncthreads();                 // all reads of z/wl done
    if (idx < 3) {
      // drain staged regs -> LDS for next pair
      #pragma unroll
      for (int k = 0; k < 3; k++) {
        int i = tid + k*256;
        if (i < 750) {
          int r2 = (i >= 375) ? 1 : 0;
          int ii = i - 375*r2;
          fx4 o;
          #pragma unroll
          for (int j = 0; j < 4; j++) o[j] = fq_int(st[k][j], inv_sv) * sv;
          *(fx4*)&z[r2][16 + 4*ii] = o;
        }
      }
      if (tid < 64 && wkk < KW) wl[wr2][wkk] = fq_int(wreg, inv_sw) * sw;
      __syncthreads();
    }
  }
  block_amax(am, amaxY);
}

// ---------- BN stats partial: exact integer sums + biased qmin/qmax, atomics ----
__global__ void bnstats_part_k(const float* __restrict__ y, const float* amaxY,
                               int* s1a, int* s2a, unsigned* qmxa, unsigned* qmna) {
  float sy = dscale(amaxY); float inv_sy = 1.0f/sy;
  int f = blockIdx.x & 511;
  int part = blockIdx.x >> 9;          // 0..3
  int s1 = 0, s2 = 0, qmn = 127, qmx = -128;
  for (int b = part*8; b < part*8 + 8; b++) {
    const fx4* base = (const fx4*)(y + ((long)b*NF + f)*NT);
    for (int i = threadIdx.x; i < NT/4; i += blockDim.x) {
      fx4 v = base[i];
      #pragma unroll
      for (int j = 0; j < 4; j++) {
        int q = (int)fq_int(v[j], inv_sy);
        s1 += q; s2 += q*q;
        qmn = min(qmn, q); qmx = max(qmx, q);
      }
    }
  }
  #pragma unroll
  for (int o = 32; o > 0; o >>= 1) {
    s1 += __shfl_xor(s1, o); s2 += __shfl_xor(s2, o);
    qmn = min(qmn, __shfl_xor(qmn, o)); qmx = max(qmx, __shfl_xor(qmx, o));
  }
  __shared__ int rs1[4], rs2[4], rmn[4], rmx[4];
  if ((threadIdx.x & 63) == 0) {
    int wv = threadIdx.x >> 6;
    rs1[wv] = s1; rs2[wv] = s2; rmn[wv] = qmn; rmx[wv] = qmx;
  }
  __syncthreads();
  if (threadIdx.x == 0) {
    int S1 = rs1[0]+rs1[1]+rs1[2]+rs1[3];
    int S2 = rs2[0]+rs2[1]+rs2[2]+rs2[3];
    int mn = min(min(rmn[0],rmn[1]), min(rmn[2],rmn[3]));
    int mx = max(max(rmx[0],rmx[1]), max(rmx[2],rmx[3]));
    atomicAdd(s1a + f, S1);
    atomicAdd(s2a + f, S2);
    atomicMax(qmxa + f, (unsigned)(mx + 128));   // biased, init 0 safe
    atomicMax(qmna + f, (unsigned)(127 - mn));   // biased, init 0 safe
  }
}

// ---------- BN finalize: mean/rinv + EXACT amaxP via discrete sweep ----------
__global__ void bnfin_k(const int* __restrict__ s1a, const int* __restrict__ s2a,
                        const unsigned* __restrict__ qmxa, const unsigned* __restrict__ qmna,
                        const float* amaxY, const float* __restrict__ bg,
                        const float* __restrict__ bb,
                        float* bn_mean, float* bn_rinv, float* amaxP) {
  int f = blockIdx.x;
  float sy = dscale(amaxY);
  __shared__ float sh_mean, sh_rinv; __shared__ int sh_qmn, sh_qmx;
  if (threadIdx.x == 0) {
    long long S1 = s1a[f];
    long long S2 = s2a[f];
    double s = (double)sy;
    double mean = (double)S1 * s / (double)NM;
    double var  = (double)S2 * s * s / (double)NM - mean*mean;
    float fm = (float)mean;
    float fr = rsqrtf((float)var + EPSF);
    bn_mean[f] = fm; bn_rinv[f] = fr;
    sh_mean = fm; sh_rinv = fr;
    sh_qmx = (int)qmxa[f] - 128;
    sh_qmn = 127 - (int)qmna[f];
  }
  __syncthreads();
  float pm = 0.f;
  int q = sh_qmn + (int)threadIdx.x;
  if (q <= sh_qmx) {
    float zq = (float)q * sy;
    float val = (zq - sh_mean)*sh_rinv*bg[f] + bb[f];
    val = val / (1.0f + expf(-val));
    pm = fabsf(val);
  }
  block_amax(pm, amaxP);
}

// ---------- BN apply + silu + transpose + quantize + packed i8 store ----------
__global__ void bnsilu_pack_k(const float* __restrict__ y, const float* __restrict__ bg,
                              const float* __restrict__ bb, const float* amaxY,
                              const float* bn_mean, const float* bn_rinv,
                              char* __restrict__ pq, const float* amaxP) {
  __shared__ float lds[32][33];     // [t][f]
  float sy = dscale(amaxY); float inv_sy = 1.0f/sy;
  float inv_sp = 1.0f / dscale(amaxP);
  int tx = threadIdx.x & 31, ty = threadIdx.x >> 5;
  const int TTILES = (NT + 31)/32;
  const int ntile = NB * (NF/32) * TTILES;
  for (int tile = blockIdx.x; tile < ntile; tile += gridDim.x) {
    int b = tile / ((NF/32)*TTILES);
    int rem = tile % ((NF/32)*TTILES);
    int fT = rem / TTILES, tT = rem % TTILES;
    int f0 = fT*32, t0 = tT*32;
    __syncthreads();
    #pragma unroll
    for (int sI = 0; sI < 4; sI++) {
      int f = f0 + ty + sI*8;
      int t = t0 + tx;
      if (t < NT) {
        float zq = fq_int(y[((long)b*NF + f)*NT + t], inv_sy) * sy;
        float val = (zq - bn_mean[f])*bn_rinv[f]*bg[f] + bb[f];
        val = val / (1.0f + expf(-val));
        lds[tx][ty + sI*8] = val;
      }
    }
    __syncthreads();
    if (threadIdx.x < 128) {
      int r = threadIdx.x >> 2;        // local t
      int c = threadIdx.x & 3;         // 8-col group within the 32-f tile
      int t = t0 + r;
      if (t < NT) {
        int lo = 0, hi = 0;
        #pragma unroll
        for (int j = 0; j < 4; j++)
          lo |= ((int)fq_int(lds[r][c*8 + j],     inv_sp) & 0xff) << (8*j);
        #pragma unroll
        for (int j = 0; j < 4; j++)
          hi |= ((int)fq_int(lds[r][c*8 + 4 + j], inv_sp) & 0xff) << (8*j);
        long bt = (long)b*NT + t;
        int q8 = (f0 >> 3) + c;          // global 8-col group, 0..63
        size_t chunk = ((size_t)(bt>>4)*8 + (q8>>3))*64 + ((q8>>1)&3)*16 + (bt&15);
        *(ix2*)(pq + chunk*16 + (q8&1)*8) = ix2{lo, hi};
      }
    }
  }
}

extern "C" void kernel_launch(void* const* d_in, const int* in_sizes, int n_in,
                              void* d_out, int out_size, void* d_ws, size_t ws_size,
                              hipStream_t stream) {
  const float* x  = (const float*)d_in[0];
  const float* lg = (const float*)d_in[1];
  const float* lb = (const float*)d_in[2];
  const float* W1 = (const float*)d_in[3];
  const float* b1 = (const float*)d_in[4];
  const float* dw = (const float*)d_in[5];
  const float* db = (const float*)d_in[6];
  const float* bg = (const float*)d_in[7];
  const float* bb = (const float*)d_in[8];
  const float* W2 = (const float*)d_in[9];
  const float* b2 = (const float*)d_in[10];
  float* out = (float*)d_out;

  char* ws = (char*)d_ws;
  float* amax    = (float*)ws;             // [0]=t [1]=W1 [2]=W2 [3]=dw [4]=u [5]=v [6]=y [7]=p [8]=r
  float* bn_mean = (float*)(ws + 1024);
  float* bn_rinv = (float*)(ws + 4096);
  int*      s1a  = (int*)(ws + 8192);
  int*      s2a  = (int*)(ws + 10240);
  unsigned* qmxa = (unsigned*)(ws + 12288);
  unsigned* qmna = (unsigned*)(ws + 14336);
  char* H = ws + 16384;
  float* uT    = (float*)H;                       // [0, 196.6M)  u transposed [1024][48000]
  char*  t_q   = H + 196608000;                   // 24.576 MB i8 packed
  float* y     = (float*)H;                       // over dead uT
  char*  p_q   = H + 221184000;                   // 24.576 MB i8 packed
  char*  W1q   = H + 245760000;                   // 512 KB
  char*  W2q   = H + 246284288;                   // 256 KB
  float* v = (float*)d_out;
  float* r = (float*)d_out;

  hipMemsetAsync(ws, 0, 16384, stream);

  absmax_w<<<392, 256, 0, stream>>>(W1, W2, dw, amax);
  quant_pack_i8<<<128, 256, 0, stream>>>(W1, W1q, 1024, amax+1);
  quant_pack_i8<<<64,  256, 0, stream>>>(W2, W2q, 512,  amax+2);

  ln_amax_k<<<1536, 256, 0, stream>>>(x, lg, lb, amax+0);
  ln_pack_k<<<3072, 256, 0, stream>>>(x, lg, lb, t_q, amax+0);
  gemm_k<8,0><<<3008, 256, 0, stream>>>(t_q, W1q, b1, uT, amax+0, amax+1, amax+4);
  glu_k<<<4096, 256, 0, stream>>>(uT, v, amax+4, amax+5);
  dwconv_k<<<2048, 256, 0, stream>>>(v, dw, db, y, amax+5, amax+3, amax+6);
  bnstats_part_k<<<2048, 256, 0, stream>>>(y, amax+6, s1a, s2a, qmxa, qmna);
  bnfin_k<<<512, 256, 0, stream>>>(s1a, s2a, qmxa, qmna, amax+6, bg, bb, bn_mean, bn_rinv, amax+7);
  bnsilu_pack_k<<<4096, 256, 0, stream>>>(y, bg, bb, amax+6, bn_mean, bn_rinv, p_q, amax+7);
  gemm_k<4,1><<<1504, 256, 0, stream>>>(p_q, W2q, b2, r, amax+7, amax+2, amax+8);
  quant_deq_f32<<<2048, 256, 0, stream>>>(out, 24576000/4, amax+8);
}